// Round 11
// baseline (35.854 us; speedup 1.0000x reference)
//
#include <hip/hip_runtime.h>
#include <math.h>
#include <stdint.h>

// NonLinearLayer: piecewise-quadratic CDF flow on a geometric mesh.
// x:(N,16) f32, pdj:(N,1), sldj:(N,1), log_p:(63,16), mesh_norm:(65,), elmt_size:(64,)
// out = concat(x_out (N*16), pdj_out (N), sldj_out (N))
//
// R11: TWO-KERNEL SPLIT. R10's pinned-prefetch crashed (compiler may spill/copy
// asm-pinned regs while their loads are in flight — unfixable at HIP level).
// Remaining structural taxes: (1) every block redid the expf+scan setup
// (~serial shuffle chains, 8-deep per CU); (2) 4 grid-stride iters serialized
// 4 latency chains per wave. Fix: setup kernel (1 block) builds the 66-row
// coef table once into d_ws; main kernel (8192 blocks, NO loop) copies the
// 18KB table L2->LDS and does ONE half-point per thread — the HW dispatcher
// pipelines wave launches (each wave's x-load issues at wave start), giving
// deep natural MLP. Sentinel bins (rows 0/65 = identity) keep the body
// branch-free: y=xn, dt=1 fall out of the quadratic exactly.

namespace {
constexpr int DIM = 16;
constexpr int ME  = 64;
constexpr float BOUNDF = 50.0f;
// K1 = 0.2/one_step = 0.02*(1.2^32-1);  INV_L2R = 1/log2(1.2)
constexpr float K1      = 6.8164378f;
constexpr float INV_L2R = 3.8017840f;
constexpr int NBIN = 66;                 // sentinel 0, real 1..64, sentinel 65
constexpr int ROWF = 68;                 // floats per row: 16 dims * 4 + pad
constexpr int TABLE_FLOATS = NBIN * ROWF; // 4488 floats = 17952 B
}

// ---------- kernel 1: build coefficient table (1 block, 256 threads) ----------
__global__ __launch_bounds__(256) void nll_setup(
    const float* __restrict__ log_p,
    const float* __restrict__ mesh_norm,
    float* __restrict__ table)
{
  __shared__ float s_mesh[ME + 1];
  const int tid = threadIdx.x;
  if (tid <= ME) s_mesh[tid] = mesh_norm[tid];
  __syncthreads();

  const int wv = tid >> 6, lane = tid & 63;
  const float mj  = s_mesh[lane];
  const float mj1 = s_mesh[lane + 1];
  const float mj2 = s_mesh[(lane + 2 > ME) ? ME : (lane + 2)];
  const float es0 = s_mesh[1] - s_mesh[0];
  const float h = mj1 - mj;

#pragma unroll
  for (int i = 0; i < 4; ++i) {
    const int d = 4 * wv + i;
    const float ep = (lane < 63) ? __expf(log_p[lane * DIM + d]) : 0.f;
    float ss = (lane < 63) ? ep * (mj2 - mj) : 0.f;
    ss += __shfl_xor(ss, 1);  ss += __shfl_xor(ss, 2);  ss += __shfl_xor(ss, 4);
    ss += __shfl_xor(ss, 8);  ss += __shfl_xor(ss, 16); ss += __shfl_xor(ss, 32);
    const float scale = (1.0f - es0) / (0.5f * ss);
    const float cur = (lane < 63) ? ep * scale : 1.0f;   // pdf_norm[lane+1]
    float prev = __shfl_up(cur, 1);                       // pdf_norm[lane]
    if (lane == 0) prev = 1.0f;
    const float cell = (prev + cur) * 0.5f * h;
    float v = cell, o;
    o = __shfl_up(v, 1);  if (lane >= 1)  v += o;
    o = __shfl_up(v, 2);  if (lane >= 2)  v += o;
    o = __shfl_up(v, 4);  if (lane >= 4)  v += o;
    o = __shfl_up(v, 8);  if (lane >= 8)  v += o;
    o = __shfl_up(v, 16); if (lane >= 16) v += o;
    o = __shfl_up(v, 32); if (lane >= 32) v += o;
    const float F = v - cell;                             // exclusive prefix = F_ref[lane]
    const float A = 0.5f * (cur - prev) / h;
    const float B = fmaf(-(A + A), mj, prev);
    const float D = fmaf(mj, fmaf(mj, A, -prev), F);
    *reinterpret_cast<float4*>(&table[(lane + 1) * ROWF + 4 * d]) =
        make_float4(A, B, D, A + A);
  }
  // sentinel rows 0 and 65: (A,B,D,2A) = (0,1,0,0) -> y=xn, dt=1 exactly
  if (tid < 32) {
    const int row = (tid >> 4) ? (NBIN - 1) : 0;
    const int d = tid & 15;
    *reinterpret_cast<float4*>(&table[row * ROWF + 4 * d]) =
        make_float4(0.f, 1.f, 0.f, 0.f);
  }
}

// ---------- kernel 2: main, one half-point (8 dims) per thread, no loop ----------
__global__ __launch_bounds__(256) void nll_main(
    const float* __restrict__ x,
    const float* __restrict__ pdj,
    const float* __restrict__ sldj,
    const float* __restrict__ table,
    float* __restrict__ out,
    int npts, int npairs)
{
  __shared__ __align__(16) float co[TABLE_FLOATS];

  const int tid = threadIdx.x;
  // L2 -> LDS table broadcast (18KB; resident in every XCD L2 after first use)
  {
    const float4* t4 = reinterpret_cast<const float4*>(table);
    float4* c4 = reinterpret_cast<float4*>(co);
#pragma unroll
    for (int i = 0; i < 5; ++i) {
      const int idx = tid + 256 * i;
      if (idx < TABLE_FLOATS / 4) c4[idx] = t4[idx];
    }
  }
  __syncthreads();

  const int t = blockIdx.x * blockDim.x + tid;
  if (t >= npairs) return;

  const float4* __restrict__ x4 = reinterpret_cast<const float4*>(x);
  float4* __restrict__ out4 = reinterpret_cast<float4*>(out);
  const int np16 = npts * DIM;

  const int p  = t >> 1;
  const int hh = t & 1;                       // half: dims hh*8 .. hh*8+7
  const int dbase = hh << 5;                  // float offset of dim block in a row
  const float4 xa = x4[2 * t];
  const float4 xb = x4[2 * t + 1];
  const float ps = hh ? sldj[p] : pdj[p];
  const float vals[8] = {xa.x, xa.y, xa.z, xa.w, xb.x, xb.y, xb.z, xb.w};

  float xn[8];
  int   idx[8];
#pragma unroll
  for (int j = 0; j < 8; ++j) {
    const float val = vals[j];
    xn[j] = fmaf(val, 0.01f, 0.5f);
    const float u = fmaf(fabsf(val), K1, 1.0f);
    const float n = __log2f(u) * INV_L2R;
    int k = 32 + (int)ceilf(copysignf(n, val));   // searchsorted k (analytic)
    k = k < 0 ? 0 : (k > NBIN - 1 ? NBIN - 1 : k);
    idx[j] = k * ROWF + dbase + (j << 2);
  }

  float4 cf[8];
#pragma unroll
  for (int j = 0; j < 8; ++j)
    cf[j] = *reinterpret_cast<const float4*>(&co[idx[j]]);

  float yv[8], dt[8];
#pragma unroll
  for (int j = 0; j < 8; ++j) {
    const float z = xn[j];
    yv[j] = fmaf(fmaf(z, fmaf(z, cf[j].x, cf[j].y), cf[j].z), 2.0f * BOUNDF, -BOUNDF);
    dt[j] = fmaf(z, cf[j].w, cf[j].y);
  }
  const float prod = ((dt[0] * dt[1]) * (dt[2] * dt[3])) *
                     ((dt[4] * dt[5]) * (dt[6] * dt[7]));

  out4[2 * t]     = make_float4(yv[0], yv[1], yv[2], yv[3]);
  out4[2 * t + 1] = make_float4(yv[4], yv[5], yv[6], yv[7]);

  const float full = prod * __shfl_xor(prod, 1);
  const float res  = hh ? (ps + __logf(full)) : (ps * full);
  out[np16 + hh * npts + p] = res;
}

extern "C" void kernel_launch(void* const* d_in, const int* in_sizes, int n_in,
                              void* d_out, int out_size, void* d_ws, size_t ws_size,
                              hipStream_t stream) {
  const float* x    = (const float*)d_in[0];
  const float* pdj  = (const float*)d_in[1];
  const float* sldj = (const float*)d_in[2];
  const float* lp   = (const float*)d_in[3];
  const float* mesh = (const float*)d_in[4];
  float* out   = (float*)d_out;
  float* table = (float*)d_ws;                 // 17952 B of scratch

  const int npts   = in_sizes[0] / DIM;
  const int npairs = npts * 2;
  const int block  = 256;
  const int grid   = (npairs + block - 1) / block;   // 8192 @ 1M points

  hipLaunchKernelGGL(nll_setup, dim3(1), dim3(block), 0, stream, lp, mesh, table);
  hipLaunchKernelGGL(nll_main, dim3(grid), dim3(block), 0, stream,
                     x, pdj, sldj, table, out, npts, npairs);
}